// Round 3
// baseline (302.322 us; speedup 1.0000x reference)
//
#include <hip/hip_runtime.h>

// PoseCost: SE(3) log-map pose error over N poses.
// in:  pos [N,3] f32, rot [N,9] f32 (row-major), goal_pos [3], goal_rot [9], vec_weight [6]
// out: cost [N], rot_err [N], pos_err [N], v [N,3], omega [N,3]  (concat flat, f32)
//
// R3 structure: 4 poses per thread, no LDS, no barriers.
//   rot for poses 4j..4j+3 = floats [36j, 36j+36) = 9 aligned float4s
//   pos = floats [12j, 12j+12) = 3 aligned float4s
//   all outputs likewise exact float4 multiples per thread.

#define BLOCK 256
#define PPT 4

struct PoseOut { float cost, re, pe, v0, v1, v2, o0, o1, o2; };

__device__ __forceinline__ PoseOut pose_compute(
    const float* __restrict__ R,      // 9 floats, row-major ee rotation
    float p0, float p1, float p2,
    const float* __restrict__ G,      // 9 floats goal rot
    float g0, float g1, float g2,
    const float* __restrict__ w)      // 6 weights
{
    PoseOut r;
    // d = goal_pos - p ; t_ge = R^T d
    const float d0 = g0 - p0, d1 = g1 - p1, d2 = g2 - p2;
    const float tq0 = R[0] * d0 + R[3] * d1 + R[6] * d2;
    const float tq1 = R[1] * d0 + R[4] * d1 + R[7] * d2;
    const float tq2 = R[2] * d0 + R[5] * d1 + R[8] * d2;

    // M = R^T * G
    float M[9];
    #pragma unroll
    for (int i = 0; i < 3; ++i)
        #pragma unroll
        for (int j = 0; j < 3; ++j)
            M[i * 3 + j] = R[0 + i] * G[0 + j] + R[3 + i] * G[3 + j] + R[6 + i] * G[6 + j];

    const float tr = M[0] + M[4] + M[8];
    float cos_t = (tr - 1.0f) * 0.5f;
    cos_t = fminf(fmaxf(cos_t, -1.0f + 1e-7f), 1.0f - 1e-7f);
    const float theta = acosf(cos_t);
    // theta in [0,pi] => sin(theta) = sqrt(1 - cos^2)
    const float sin_t = sqrtf(fmaxf(1.0f - cos_t * cos_t, 0.0f));

    const float wv0 = 0.5f * (M[7] - M[5]);
    const float wv1 = 0.5f * (M[2] - M[6]);
    const float wv2 = 0.5f * (M[3] - M[1]);

    const bool small = theta < 1e-4f;
    const float th2 = theta * theta;
    const float scale = small ? (1.0f + th2 * (1.0f / 6.0f)) : (theta / sin_t);
    const float o0 = scale * wv0, o1 = scale * wv1, o2 = scale * wv2;

    const float theta2 = small ? 1.0f : th2;
    const float A = small ? (1.0f / 12.0f)
                          : (1.0f - (theta * sin_t) / (2.0f * (1.0f - cos_t))) / theta2;

    // v = t - 0.5*(omega x t) + A*(omega*(omega.t) - |omega|^2 t)
    const float cx0 = o1 * tq2 - o2 * tq1;
    const float cx1 = o2 * tq0 - o0 * tq2;
    const float cx2 = o0 * tq1 - o1 * tq0;
    const float odt = o0 * tq0 + o1 * tq1 + o2 * tq2;
    const float on2 = o0 * o0 + o1 * o1 + o2 * o2;
    const float v0 = tq0 - 0.5f * cx0 + A * (o0 * odt - on2 * tq0);
    const float v1 = tq1 - 0.5f * cx1 + A * (o1 * odt - on2 * tq1);
    const float v2 = tq2 - 0.5f * cx2 + A * (o2 * odt - on2 * tq2);

    const float we0 = w[0] * o0, we1 = w[1] * o1, we2 = w[2] * o2;
    const float wp0 = w[3] * v0, wp1 = w[4] * v1, wp2 = w[5] * v2;
    float re = we0 * we0 + we1 * we1 + we2 * we2;
    float pe = wp0 * wp0 + wp1 * wp1 + wp2 * wp2;
    re = (re < 0.0f) ? 0.0f : re;   // CONV_* = 0: exact where() semantics
    pe = (pe < 0.0f) ? 0.0f : pe;
    r.cost = 15.0f * re + 100.0f * pe;
    r.re = re; r.pe = pe;
    r.v0 = v0; r.v1 = v1; r.v2 = v2;
    r.o0 = o0; r.o1 = o1; r.o2 = o2;
    return r;
}

__global__ __launch_bounds__(BLOCK) void pose_cost_kernel(
    const float* __restrict__ pos,
    const float* __restrict__ rot,
    const float* __restrict__ gpos,
    const float* __restrict__ grot,
    const float* __restrict__ wvec,
    float* __restrict__ out,
    int N, int vecOK)
{
    const int j = blockIdx.x * BLOCK + threadIdx.x;   // thread -> poses 4j..4j+3
    const int p0 = j * PPT;
    if (p0 >= N) return;

    // uniform (wave-invariant) goal / weight data -> scalar loads
    float G[9], g0, g1, g2, w[6];
    #pragma unroll
    for (int k = 0; k < 9; ++k) G[k] = grot[k];
    g0 = gpos[0]; g1 = gpos[1]; g2 = gpos[2];
    #pragma unroll
    for (int k = 0; k < 6; ++k) w[k] = wvec[k];

    if (vecOK && (p0 + PPT) <= N) {
        // ---- 12 independent dwordx4 loads, no barriers ----
        float Rf[36], Pf[12];
        {
            const float4* r4 = (const float4*)(rot + (size_t)p0 * 9);
            #pragma unroll
            for (int k = 0; k < 9; ++k) {
                const float4 x = r4[k];
                Rf[4 * k + 0] = x.x; Rf[4 * k + 1] = x.y;
                Rf[4 * k + 2] = x.z; Rf[4 * k + 3] = x.w;
            }
            const float4* pp = (const float4*)(pos + (size_t)p0 * 3);
            #pragma unroll
            for (int k = 0; k < 3; ++k) {
                const float4 x = pp[k];
                Pf[4 * k + 0] = x.x; Pf[4 * k + 1] = x.y;
                Pf[4 * k + 2] = x.z; Pf[4 * k + 3] = x.w;
            }
        }

        float c[4], re[4], pe[4], vv[12], oo[12];
        #pragma unroll
        for (int q = 0; q < PPT; ++q) {
            PoseOut o = pose_compute(&Rf[9 * q], Pf[3 * q + 0], Pf[3 * q + 1], Pf[3 * q + 2],
                                     G, g0, g1, g2, w);
            c[q] = o.cost; re[q] = o.re; pe[q] = o.pe;
            vv[3 * q + 0] = o.v0; vv[3 * q + 1] = o.v1; vv[3 * q + 2] = o.v2;
            oo[3 * q + 0] = o.o0; oo[3 * q + 1] = o.o1; oo[3 * q + 2] = o.o2;
        }

        // ---- exact float4 stores ----
        *(float4*)(out + p0)                 = make_float4(c[0], c[1], c[2], c[3]);
        *(float4*)(out + (size_t)N + p0)     = make_float4(re[0], re[1], re[2], re[3]);
        *(float4*)(out + 2 * (size_t)N + p0) = make_float4(pe[0], pe[1], pe[2], pe[3]);
        float* vdst = out + 3 * (size_t)N + (size_t)p0 * 3;
        float* odst = out + 6 * (size_t)N + (size_t)p0 * 3;
        #pragma unroll
        for (int k = 0; k < 3; ++k) {
            *(float4*)(vdst + 4 * k) = make_float4(vv[4 * k], vv[4 * k + 1], vv[4 * k + 2], vv[4 * k + 3]);
            *(float4*)(odst + 4 * k) = make_float4(oo[4 * k], oo[4 * k + 1], oo[4 * k + 2], oo[4 * k + 3]);
        }
    } else {
        // scalar tail: up to 4 poses, each guarded
        #pragma unroll
        for (int q = 0; q < PPT; ++q) {
            const int i = p0 + q;
            if (i >= N) break;
            float R[9];
            #pragma unroll
            for (int k = 0; k < 9; ++k) R[k] = rot[(size_t)i * 9 + k];
            const float pp0 = pos[(size_t)i * 3 + 0];
            const float pp1 = pos[(size_t)i * 3 + 1];
            const float pp2 = pos[(size_t)i * 3 + 2];
            PoseOut o = pose_compute(R, pp0, pp1, pp2, G, g0, g1, g2, w);
            out[i] = o.cost;
            out[(size_t)N + i] = o.re;
            out[2 * (size_t)N + i] = o.pe;
            out[3 * (size_t)N + (size_t)i * 3 + 0] = o.v0;
            out[3 * (size_t)N + (size_t)i * 3 + 1] = o.v1;
            out[3 * (size_t)N + (size_t)i * 3 + 2] = o.v2;
            out[6 * (size_t)N + (size_t)i * 3 + 0] = o.o0;
            out[6 * (size_t)N + (size_t)i * 3 + 1] = o.o1;
            out[6 * (size_t)N + (size_t)i * 3 + 2] = o.o2;
        }
    }
}

extern "C" void kernel_launch(void* const* d_in, const int* in_sizes, int n_in,
                              void* d_out, int out_size, void* d_ws, size_t ws_size,
                              hipStream_t stream) {
    const float* pos  = (const float*)d_in[0];   // [N,3]
    const float* rot  = (const float*)d_in[1];   // [N,9]
    const float* gpos = (const float*)d_in[2];   // [3]
    const float* grot = (const float*)d_in[3];   // [9]
    const float* wv   = (const float*)d_in[4];   // [6]
    float* out = (float*)d_out;

    const int N = in_sizes[0] / 3;
    const int vecOK = (N % 4 == 0) ? 1 : 0;      // float4 paths need N%4==0
    const int threads_needed = (N + PPT - 1) / PPT;
    const int blocks = (threads_needed + BLOCK - 1) / BLOCK;
    hipLaunchKernelGGL(pose_cost_kernel, dim3(blocks), dim3(BLOCK), 0, stream,
                       pos, rot, gpos, grot, wv, out, N, vecOK);
}